// Round 8
// baseline (122.941 us; speedup 1.0000x reference)
//
#include <hip/hip_runtime.h>
#include <cstdint>
#include <cstddef>

// GraphAttentionLayer fused: B=8, N=2048, D=256
//  k_pre:  heterogeneous pre-pass. Blocks 0..1023: adj (134 MB {0,1}) -> 4 MiB
//          bitmap (HBM-bound). Blocks 1024..1279: Wh = h @ W^T (bf16 MFMA),
//          WhT[b][d][n] bf16 + s1,s2 f32 (compute-bound, hides under pack).
//  k_attn: out[i,:] = (sum_j exp(lrelu(s1_i+s2_j))*mask_ij * Wh[j,:]) / l_i
//    v8: v7 + bfr (WhT) register double-buffer across the raw counted-vmcnt
//        barrier — next chunk's 8 B-frag loads issue a full chunk (~700 cy)
//        before use, hiding L2 latency. afr consumed per-ks to cut live VGPRs.

#define NB 8
#define NN 2048
#define ND 256
#define ALPHA_F 0.2f
#define JC 64          // j per chunk
#define NCH 16         // chunks per j-group (1024/64)

typedef __attribute__((ext_vector_type(8))) short short8;   // bf16x8 MFMA frag
typedef __attribute__((ext_vector_type(4))) float f32x4;    // MFMA acc frag
typedef __attribute__((ext_vector_type(4))) int   i32x4;

__device__ __forceinline__ unsigned short f2bf(float f) {
  union { float f; unsigned int u; } v; v.f = f;
  unsigned int r = v.u + 0x7FFFu + ((v.u >> 16) & 1u);   // RNE
  return (unsigned short)(r >> 16);
}

__device__ __forceinline__ short8 pack8(const float* v) {
  short8 r;
#pragma unroll
  for (int e = 0; e < 8; ++e) r[e] = (short)f2bf(v[e]);
  return r;
}

__device__ __forceinline__ unsigned int cvtpk(float lo, float hi) {
  unsigned int r;
  asm("v_cvt_pk_bf16_f32 %0, %1, %2" : "=v"(r) : "v"(lo), "v"(hi));
  return r;
}

// ---------------- kernel 0+1 fused: pack (0..1023) | wh (1024..1279) -------
__global__ __launch_bounds__(256) void k_pre(
    const int* __restrict__ adj, i32x4* __restrict__ adjbits,
    const float* __restrict__ h, const float* __restrict__ W,
    const float* __restrict__ a,
    unsigned short* __restrict__ WhT, float* __restrict__ s1g,
    float* __restrict__ s2g)
{
  __shared__ float sl1[64], sl2[64];
  const int tid = threadIdx.x;

  if (blockIdx.x < 1024) {
    // ---- pack: adj -> bitmap, per-thread i32x4 in k_attn's consume layout --
    const int row  = tid >> 3;          // 0..31
    const int jseg = tid & 7;           // 0..7
    const int bid  = blockIdx.x;        // (b<<7) | (jg<<6) | rb
    const int rb   = bid & 63;
    const int jg   = (bid >> 6) & 1;
    const int b    = bid >> 7;
    const int i    = rb * 32 + row;
    const int* ap0 = adj + ((size_t)b * NN + i) * NN + jg * (NN / 2) + jseg * 8;

    unsigned int w[4];
#pragma unroll
    for (int r = 0; r < 4; ++r) {
      i32x4 t0[4], t1[4];
#pragma unroll
      for (int cc = 0; cc < 4; ++cc) {
        const int* ap = ap0 + (r * 4 + cc) * JC;
        t0[cc] = *(const i32x4*)ap;
        t1[cc] = *(const i32x4*)(ap + 4);
      }
      unsigned int m = 0;
#pragma unroll
      for (int cc = 0; cc < 4; ++cc)
#pragma unroll
        for (int e = 0; e < 4; ++e) {
          m |= ((unsigned int)t0[cc][e]) << (cc * 8 + e);
          m |= ((unsigned int)t1[cc][e]) << (cc * 8 + 4 + e);
        }
      w[r] = m;
    }
    i32x4 wv;
    wv[0] = (int)w[0]; wv[1] = (int)w[1]; wv[2] = (int)w[2]; wv[3] = (int)w[3];
    adjbits[(((size_t)b * 2 + jg) * NN + i) * 8 + jseg] = wv;
    return;
  }

  // ---- wh: Wh = h @ W^T, s1/s2 from f32 acc, WhT store -------------------
  const int wid  = tid >> 6;
  const int lane = tid & 63;
  const int l15  = lane & 15;
  const int c    = lane >> 4;
  const int r0   = (blockIdx.x - 1024) * 64;   // flattened (b,n) row base
  const int b    = r0 >> 11;
  const int n0   = r0 & 2047;

  if (tid < 64) { sl1[tid] = 0.f; sl2[tid] = 0.f; }

  f32x4 acc[4][4] = {};

  const float* hb = h + (size_t)r0 * ND;
  const int ocol0 = wid * 64;

  for (int k0 = 0; k0 < ND; k0 += 32) {
    short8 afr[4], bfr[4];
#pragma unroll
    for (int mi = 0; mi < 4; ++mi) {
      const float* p = hb + (size_t)(mi * 16 + l15) * ND + k0 + c * 8;
      float t[8];
      *(f32x4*)t       = *(const f32x4*)p;
      *(f32x4*)(t + 4) = *(const f32x4*)(p + 4);
      afr[mi] = pack8(t);
    }
#pragma unroll
    for (int ni = 0; ni < 4; ++ni) {
      const int o = ocol0 + ni * 16 + l15;
      const float* p = W + (size_t)o * ND + k0 + c * 8;
      float t[8];
      *(f32x4*)t       = *(const f32x4*)p;
      *(f32x4*)(t + 4) = *(const f32x4*)(p + 4);
      bfr[ni] = pack8(t);
    }
#pragma unroll
    for (int mi = 0; mi < 4; ++mi)
#pragma unroll
      for (int ni = 0; ni < 4; ++ni)
        acc[mi][ni] = __builtin_amdgcn_mfma_f32_16x16x32_bf16(
            afr[mi], bfr[ni], acc[mi][ni], 0, 0, 0);
  }

  float a1v[4], a2v[4];
#pragma unroll
  for (int ni = 0; ni < 4; ++ni) {
    const int o = ocol0 + ni * 16 + l15;
    a1v[ni] = a[o];
    a2v[ni] = a[ND + o];
  }
  float p1[4][4] = {}, p2[4][4] = {};
#pragma unroll
  for (int mi = 0; mi < 4; ++mi)
#pragma unroll
    for (int ni = 0; ni < 4; ++ni)
#pragma unroll
      for (int r = 0; r < 4; ++r) {
        p1[mi][r] += acc[mi][ni][r] * a1v[ni];
        p2[mi][r] += acc[mi][ni][r] * a2v[ni];
      }
#pragma unroll
  for (int m = 1; m <= 8; m <<= 1) {
#pragma unroll
    for (int mi = 0; mi < 4; ++mi)
#pragma unroll
      for (int r = 0; r < 4; ++r) {
        p1[mi][r] += __shfl_xor(p1[mi][r], m, 64);
        p2[mi][r] += __shfl_xor(p2[mi][r], m, 64);
      }
  }
  __syncthreads();
  if (l15 == 0) {
#pragma unroll
    for (int mi = 0; mi < 4; ++mi)
#pragma unroll
      for (int r = 0; r < 4; ++r) {
        atomicAdd(&sl1[mi * 16 + c * 4 + r], p1[mi][r]);
        atomicAdd(&sl2[mi * 16 + c * 4 + r], p2[mi][r]);
      }
  }

#pragma unroll
  for (int mi = 0; mi < 4; ++mi)
#pragma unroll
    for (int ni = 0; ni < 4; ++ni) {
      const int o = ocol0 + ni * 16 + l15;
      const int n = n0 + mi * 16 + c * 4;
      unsigned short u4[4];
#pragma unroll
      for (int r = 0; r < 4; ++r) u4[r] = f2bf(acc[mi][ni][r]);
      *(uint2*)(WhT + ((size_t)b * ND + o) * NN + n) = *(uint2*)u4;
    }
  __syncthreads();
  if (tid < 64) { s1g[r0 + tid] = sl1[tid]; s2g[r0 + tid] = sl2[tid]; }
}

// ---------------- kernel 2: fused masked-exp attention GEMM (v8) -----------
// grid: 512 blocks 1D (b = bid&7 for XCD/L2 locality), 512 thr (8 waves).
// Wave wid: j-group = wid>>2 (half of j-range), col-group = wid&3 (64 cols).
// Per chunk of 64 j: 256 threads of a j-group build P[32][64] bf16 in LDS
// (swizzled) gated by prologue-loaded bitmap bits; the 4 waves consume P as
// MFMA A-frags. Double-buffered pbuf AND register-double-buffered bfr: next
// chunk's WhT frag loads issue one full chunk before use, staying in flight
// across the raw (lgkmcnt-only) barrier.
__global__ __launch_bounds__(512, 4) void k_attn(
    const i32x4* __restrict__ adjbits, const unsigned short* __restrict__ WhT,
    const float* __restrict__ s1g, const float* __restrict__ s2g,
    float* __restrict__ out)
{
  __shared__ __align__(16) char smem[32 * 1024 + 128];
  float*          s2s  = (float*)smem;                       // [0, 8K)
  unsigned short* pbuf = (unsigned short*)(smem + 8 * 1024); // [8K,24K): [jg][buf][32][64]
  float*          lsml = (float*)(smem + 32 * 1024);         // [32K, +128)
  float*          comb = (float*)smem;                       // [0,32K) alias after loop

  const int tid  = threadIdx.x;
  const int wid  = tid >> 6;
  const int lane = tid & 63;
  const int l15  = lane & 15;
  const int c    = lane >> 4;
  const int bid  = blockIdx.x;
  const int b    = bid & 7;           // batch -> XCD residue (L2 locality)
  const int i0   = (bid >> 3) * 32;

  // build-phase thread mapping
  const int lt     = tid & 255;
  const int jg     = tid >> 8;        // j-group 0/1 (== wid>>2)
  const int row    = lt & 31;
  const int jseg   = lt >> 5;         // 0..7, 8 j's each
  const int jgbase = jg * (NN / 2);
  const int gsw    = jseg ^ (row & 7);          // swizzled 16B granule
  const int wcol   = wid & 3;

  if (tid < 32) lsml[tid] = 0.f;
  { // stage s2[b][:] into LDS
    const f32x4* src = (const f32x4*)(s2g + (size_t)b * NN);
    f32x4* dst = (f32x4*)s2s;
    for (int t = tid; t < NN / 4; t += 512) dst[t] = src[t];
  }
  const float s1r = s1g[(size_t)b * NN + i0 + row];

  // masks for all 16 chunks: one 16-B load (byte ch of qw[ch>>2])
  const i32x4 qw = adjbits[(((size_t)b * 2 + jg) * NN + (i0 + row)) * 8 + jseg];

  f32x4 acc[2][4] = {};
  float lacc = 0.f;

  const unsigned short* wb = WhT + ((size_t)b * ND + wcol * 64) * NN;
  unsigned short* pbW[2] = { pbuf + (jg * 2 + 0) * 2048, pbuf + (jg * 2 + 1) * 2048 };

  short8 bfr[2][2][4];   // [slot][ks][ni] register double-buffer of WhT frags

#define LOADB(CH, SL)                                                        \
  {                                                                          \
    _Pragma("unroll")                                                        \
    for (int ks = 0; ks < 2; ++ks)                                           \
      _Pragma("unroll")                                                      \
      for (int ni = 0; ni < 4; ++ni)                                         \
        bfr[SL][ks][ni] = *(const short8*)(wb + (size_t)(ni * 16 + l15) * NN + \
                                           jgbase + (CH) * JC + ks * 32 + c * 8); \
  }

#define BUILDC(CH, BB)                                                       \
  {                                                                          \
    const unsigned int mwv = (unsigned int)qw[(CH) >> 2];                    \
    const float* s2p = s2s + jgbase + (CH) * JC + jseg * 8;                  \
    f32x4 sa = *(const f32x4*)s2p;                                           \
    f32x4 sb = *(const f32x4*)(s2p + 4);                                     \
    float pv[8];                                                             \
    _Pragma("unroll")                                                        \
    for (int e = 0; e < 4; ++e) {                                            \
      float ev = s1r + sa[e];                                                \
      ev = fmaxf(ev, ALPHA_F * ev);                                          \
      pv[e] = ((mwv >> (((CH) & 3) * 8 + e)) & 1u) ? __expf(ev) : 0.f;       \
    }                                                                        \
    _Pragma("unroll")                                                        \
    for (int e = 0; e < 4; ++e) {                                            \
      float ev = s1r + sb[e];                                                \
      ev = fmaxf(ev, ALPHA_F * ev);                                          \
      pv[4 + e] = ((mwv >> (((CH) & 3) * 8 + 4 + e)) & 1u) ? __expf(ev) : 0.f; \
    }                                                                        \
    lacc += ((pv[0] + pv[1]) + (pv[2] + pv[3])) +                            \
            ((pv[4] + pv[5]) + (pv[6] + pv[7]));                             \
    i32x4 pk;                                                                \
    pk[0] = (int)cvtpk(pv[0], pv[1]);                                        \
    pk[1] = (int)cvtpk(pv[2], pv[3]);                                        \
    pk[2] = (int)cvtpk(pv[4], pv[5]);                                        \
    pk[3] = (int)cvtpk(pv[6], pv[7]);                                        \
    *(i32x4*)(pbW[BB] + row * 64 + gsw * 8) = pk;                            \
  }

  // raw barrier: drain LDS ops only; global loads stay counted (T4)
#define CHUNK_BARRIER()                                                      \
  { asm volatile("s_waitcnt lgkmcnt(0)" ::: "memory");                       \
    __builtin_amdgcn_s_barrier(); }

  __syncthreads();   // s2s + lsml ready

  BUILDC(0, 0)
  LOADB(0, 0)        // chunk 0's bfr: issued before barrier, used after
  CHUNK_BARRIER()

#pragma unroll
  for (int ch = 0; ch < NCH; ++ch) {
    const int bb = ch & 1;
    const unsigned short* pbR = pbW[bb];
    // issue next chunk's bfr first (longest latency, hidden by BUILD+MFMA)
    if (ch + 1 < NCH) LOADB(ch + 1, (ch + 1) & 1)
    if (ch + 1 < NCH) BUILDC(ch + 1, (ch + 1) & 1)
    // consume current bfr (in flight since previous iteration)
#pragma unroll
    for (int ks = 0; ks < 2; ++ks) {
      short8 a0 = *(const short8*)(pbR + (0 * 16 + l15) * 64 +
                                   (((ks * 4 + c) ^ (l15 & 7)) * 8));
      short8 a1 = *(const short8*)(pbR + (1 * 16 + l15) * 64 +
                                   (((ks * 4 + c) ^ (l15 & 7)) * 8));
#pragma unroll
      for (int ni = 0; ni < 4; ++ni) {
        acc[0][ni] = __builtin_amdgcn_mfma_f32_16x16x32_bf16(
            a0, bfr[bb][ks][ni], acc[0][ni], 0, 0, 0);
        acc[1][ni] = __builtin_amdgcn_mfma_f32_16x16x32_bf16(
            a1, bfr[bb][ks][ni], acc[1][ni], 0, 0, 0);
      }
    }
    CHUNK_BARRIER()
  }

  // lsum: pre-reduce the duplicate row within the wave, then one atomic
  lacc += __shfl_xor(lacc, 32, 64);
  if (lane < 32) atomicAdd(&lsml[row], lacc);
  __syncthreads();

  // combine j-group partial accumulators via LDS
  if (jg == 1) {
#pragma unroll
    for (int mi = 0; mi < 2; ++mi)
#pragma unroll
      for (int r = 0; r < 4; ++r) {
        const int rr = mi * 16 + c * 4 + r;
#pragma unroll
        for (int ni = 0; ni < 4; ++ni)
          comb[rr * ND + wcol * 64 + ni * 16 + l15] = acc[mi][ni][r];
      }
  }
  __syncthreads();
  if (jg == 0) {
    float* ob = out + ((size_t)b * NN + i0) * ND + wcol * 64;
#pragma unroll
    for (int mi = 0; mi < 2; ++mi)
#pragma unroll
      for (int r = 0; r < 4; ++r) {
        const int rr = mi * 16 + c * 4 + r;
        const float linv = 1.0f / lsml[rr];
#pragma unroll
        for (int ni = 0; ni < 4; ++ni) {
          const float v = acc[mi][ni][r] + comb[rr * ND + wcol * 64 + ni * 16 + l15];
          ob[(size_t)rr * ND + ni * 16 + l15] = v * linv;
        }
      }
  }
#undef BUILDC
#undef LOADB
#undef CHUNK_BARRIER
}

extern "C" void kernel_launch(void* const* d_in, const int* in_sizes, int n_in,
                              void* d_out, int out_size, void* d_ws, size_t ws_size,
                              hipStream_t stream) {
  const float* h   = (const float*)d_in[0];
  const int*   adj = (const int*)d_in[1];
  const float* W   = (const float*)d_in[2];
  const float* a   = (const float*)d_in[3];
  float* out = (float*)d_out;

  unsigned short* WhT = (unsigned short*)d_ws;                       // 8 MB bf16
  float* s1g = (float*)((char*)d_ws + (size_t)NB * ND * NN * 2);     // 64 KB
  float* s2g = s1g + (size_t)NB * NN;                                // 64 KB
  i32x4* adjbits = (i32x4*)(s2g + (size_t)NB * NN);                  // 4 MB

  k_pre<<<dim3(1024 + NB * NN / 64), dim3(256), 0, stream>>>(
      adj, adjbits, h, W, a, WhT, s1g, s2g);
  k_attn<<<dim3(NB * NN / 32), dim3(512), 0, stream>>>(adjbits, WhT, s1g, s2g, out);
}

// Round 9
// 98.870 us; speedup vs baseline: 1.2435x; 1.2435x over previous
//
#include <hip/hip_runtime.h>
#include <cstdint>
#include <cstddef>

// GraphAttentionLayer fused: B=8, N=2048, D=256
//  k_pre:  heterogeneous pre-pass. Blocks 0..255: Wh = h @ W^T (bf16 MFMA) ->
//          WhT[b][d][n] bf16 + s1,s2 f32 (compute, dispatched FIRST so it
//          overlaps the pack stream). Blocks 256..2303: adj (134 MB {0,1}) ->
//          4 MiB bitmap; 16 independent 16-B loads in flight per thread
//          (R8's 8-loads-then-drain structure was MLP-starved at ~1.6 TB/s).
//  k_attn: out[i,:] = (sum_j exp(lrelu(s1_i+s2_j))*mask_ij * Wh[j,:]) / l_i
//          (v8 structure, unchanged: P built once in LDS, bitmap masks from
//          registers, bfr register double-buffer across raw counted barriers.)

#define NB 8
#define NN 2048
#define ND 256
#define ALPHA_F 0.2f
#define JC 64          // j per chunk
#define NCH 16         // chunks per j-group (1024/64)
#define WHB 256        // wh blocks (NB*NN/64)

typedef __attribute__((ext_vector_type(8))) short short8;   // bf16x8 MFMA frag
typedef __attribute__((ext_vector_type(4))) float f32x4;    // MFMA acc frag
typedef __attribute__((ext_vector_type(4))) int   i32x4;

__device__ __forceinline__ unsigned short f2bf(float f) {
  union { float f; unsigned int u; } v; v.f = f;
  unsigned int r = v.u + 0x7FFFu + ((v.u >> 16) & 1u);   // RNE
  return (unsigned short)(r >> 16);
}

__device__ __forceinline__ short8 pack8(const float* v) {
  short8 r;
#pragma unroll
  for (int e = 0; e < 8; ++e) r[e] = (short)f2bf(v[e]);
  return r;
}

__device__ __forceinline__ unsigned int cvtpk(float lo, float hi) {
  unsigned int r;
  asm("v_cvt_pk_bf16_f32 %0, %1, %2" : "=v"(r) : "v"(lo), "v"(hi));
  return r;
}

// ---------------- kernel 0+1 fused: wh (0..255) | pack (256..2303) ---------
__global__ __launch_bounds__(256) void k_pre(
    const int* __restrict__ adj, uint2* __restrict__ adjbits2,
    const float* __restrict__ h, const float* __restrict__ W,
    const float* __restrict__ a,
    unsigned short* __restrict__ WhT, float* __restrict__ s1g,
    float* __restrict__ s2g)
{
  __shared__ float sl1[64], sl2[64];
  const int tid = threadIdx.x;

  if (blockIdx.x >= WHB) {
    // ---- pack: adj -> bitmap. Thread (row,jseg) covers 8 chunks (half of
    // the 16), 16 independent 16-B loads issued before any consumption. ----
    const int pb   = blockIdx.x - WHB;  // (b<<8)|(jg<<7)|(half<<6)|rb
    const int rb   = pb & 63;
    const int half = (pb >> 6) & 1;
    const int jg   = (pb >> 7) & 1;
    const int b    = pb >> 8;
    const int row  = tid >> 3;          // 0..31
    const int jseg = tid & 7;           // 0..7
    const int i    = rb * 32 + row;
    const int* ap0 = adj + ((size_t)b * NN + i) * NN + jg * (NN / 2) +
                     half * 8 * JC + jseg * 8;

    i32x4 t0[8], t1[8];
#pragma unroll
    for (int cc = 0; cc < 8; ++cc) {
      const int* ap = ap0 + cc * JC;
      t0[cc] = *(const i32x4*)ap;
      t1[cc] = *(const i32x4*)(ap + 4);
    }
    unsigned int w0 = 0, w1 = 0;
#pragma unroll
    for (int cc = 0; cc < 4; ++cc)
#pragma unroll
      for (int e = 0; e < 4; ++e) {
        w0 |= ((unsigned int)t0[cc][e])     << (cc * 8 + e);
        w0 |= ((unsigned int)t1[cc][e])     << (cc * 8 + 4 + e);
        w1 |= ((unsigned int)t0[4 + cc][e]) << (cc * 8 + e);
        w1 |= ((unsigned int)t1[4 + cc][e]) << (cc * 8 + 4 + e);
      }
    uint2 o; o.x = w0; o.y = w1;
    adjbits2[((((size_t)b * 2 + jg) * NN + i) * 8 + jseg) * 2 + half] = o;
    return;
  }

  // ---- wh: Wh = h @ W^T, s1/s2 from f32 acc, WhT store -------------------
  const int wid  = tid >> 6;
  const int lane = tid & 63;
  const int l15  = lane & 15;
  const int c    = lane >> 4;
  const int r0   = blockIdx.x * 64;   // flattened (b,n) row base
  const int b    = r0 >> 11;
  const int n0   = r0 & 2047;

  if (tid < 64) { sl1[tid] = 0.f; sl2[tid] = 0.f; }

  f32x4 acc[4][4] = {};

  const float* hb = h + (size_t)r0 * ND;
  const int ocol0 = wid * 64;

  for (int k0 = 0; k0 < ND; k0 += 32) {
    short8 afr[4], bfr[4];
#pragma unroll
    for (int mi = 0; mi < 4; ++mi) {
      const float* p = hb + (size_t)(mi * 16 + l15) * ND + k0 + c * 8;
      float t[8];
      *(f32x4*)t       = *(const f32x4*)p;
      *(f32x4*)(t + 4) = *(const f32x4*)(p + 4);
      afr[mi] = pack8(t);
    }
#pragma unroll
    for (int ni = 0; ni < 4; ++ni) {
      const int o = ocol0 + ni * 16 + l15;
      const float* p = W + (size_t)o * ND + k0 + c * 8;
      float t[8];
      *(f32x4*)t       = *(const f32x4*)p;
      *(f32x4*)(t + 4) = *(const f32x4*)(p + 4);
      bfr[ni] = pack8(t);
    }
#pragma unroll
    for (int mi = 0; mi < 4; ++mi)
#pragma unroll
      for (int ni = 0; ni < 4; ++ni)
        acc[mi][ni] = __builtin_amdgcn_mfma_f32_16x16x32_bf16(
            afr[mi], bfr[ni], acc[mi][ni], 0, 0, 0);
  }

  float a1v[4], a2v[4];
#pragma unroll
  for (int ni = 0; ni < 4; ++ni) {
    const int o = ocol0 + ni * 16 + l15;
    a1v[ni] = a[o];
    a2v[ni] = a[ND + o];
  }
  float p1[4][4] = {}, p2[4][4] = {};
#pragma unroll
  for (int mi = 0; mi < 4; ++mi)
#pragma unroll
    for (int ni = 0; ni < 4; ++ni)
#pragma unroll
      for (int r = 0; r < 4; ++r) {
        p1[mi][r] += acc[mi][ni][r] * a1v[ni];
        p2[mi][r] += acc[mi][ni][r] * a2v[ni];
      }
#pragma unroll
  for (int m = 1; m <= 8; m <<= 1) {
#pragma unroll
    for (int mi = 0; mi < 4; ++mi)
#pragma unroll
      for (int r = 0; r < 4; ++r) {
        p1[mi][r] += __shfl_xor(p1[mi][r], m, 64);
        p2[mi][r] += __shfl_xor(p2[mi][r], m, 64);
      }
  }
  __syncthreads();
  if (l15 == 0) {
#pragma unroll
    for (int mi = 0; mi < 4; ++mi)
#pragma unroll
      for (int r = 0; r < 4; ++r) {
        atomicAdd(&sl1[mi * 16 + c * 4 + r], p1[mi][r]);
        atomicAdd(&sl2[mi * 16 + c * 4 + r], p2[mi][r]);
      }
  }

#pragma unroll
  for (int mi = 0; mi < 4; ++mi)
#pragma unroll
    for (int ni = 0; ni < 4; ++ni) {
      const int o = ocol0 + ni * 16 + l15;
      const int n = n0 + mi * 16 + c * 4;
      unsigned short u4[4];
#pragma unroll
      for (int r = 0; r < 4; ++r) u4[r] = f2bf(acc[mi][ni][r]);
      *(uint2*)(WhT + ((size_t)b * ND + o) * NN + n) = *(uint2*)u4;
    }
  __syncthreads();
  if (tid < 64) { s1g[r0 + tid] = sl1[tid]; s2g[r0 + tid] = sl2[tid]; }
}

// ---------------- kernel 2: fused masked-exp attention GEMM (v8) -----------
// grid: 512 blocks 1D (b = bid&7 for XCD/L2 locality), 512 thr (8 waves).
// Wave wid: j-group = wid>>2 (half of j-range), col-group = wid&3 (64 cols).
// Per chunk of 64 j: 256 threads of a j-group build P[32][64] bf16 in LDS
// (swizzled) gated by prologue-loaded bitmap bits; the 4 waves consume P as
// MFMA A-frags. Double-buffered pbuf AND register-double-buffered bfr: next
// chunk's WhT frag loads issue one full chunk before use, staying in flight
// across the raw (lgkmcnt-only) barrier.
__global__ __launch_bounds__(512, 4) void k_attn(
    const i32x4* __restrict__ adjbits, const unsigned short* __restrict__ WhT,
    const float* __restrict__ s1g, const float* __restrict__ s2g,
    float* __restrict__ out)
{
  __shared__ __align__(16) char smem[32 * 1024 + 128];
  float*          s2s  = (float*)smem;                       // [0, 8K)
  unsigned short* pbuf = (unsigned short*)(smem + 8 * 1024); // [8K,24K): [jg][buf][32][64]
  float*          lsml = (float*)(smem + 32 * 1024);         // [32K, +128)
  float*          comb = (float*)smem;                       // [0,32K) alias after loop

  const int tid  = threadIdx.x;
  const int wid  = tid >> 6;
  const int lane = tid & 63;
  const int l15  = lane & 15;
  const int c    = lane >> 4;
  const int bid  = blockIdx.x;
  const int b    = bid & 7;           // batch -> XCD residue (L2 locality)
  const int i0   = (bid >> 3) * 32;

  // build-phase thread mapping
  const int lt     = tid & 255;
  const int jg     = tid >> 8;        // j-group 0/1 (== wid>>2)
  const int row    = lt & 31;
  const int jseg   = lt >> 5;         // 0..7, 8 j's each
  const int jgbase = jg * (NN / 2);
  const int gsw    = jseg ^ (row & 7);          // swizzled 16B granule
  const int wcol   = wid & 3;

  if (tid < 32) lsml[tid] = 0.f;
  { // stage s2[b][:] into LDS
    const f32x4* src = (const f32x4*)(s2g + (size_t)b * NN);
    f32x4* dst = (f32x4*)s2s;
    for (int t = tid; t < NN / 4; t += 512) dst[t] = src[t];
  }
  const float s1r = s1g[(size_t)b * NN + i0 + row];

  // masks for all 16 chunks: one 16-B load (byte ch of qw[ch>>2])
  const i32x4 qw = adjbits[(((size_t)b * 2 + jg) * NN + (i0 + row)) * 8 + jseg];

  f32x4 acc[2][4] = {};
  float lacc = 0.f;

  const unsigned short* wb = WhT + ((size_t)b * ND + wcol * 64) * NN;
  unsigned short* pbW[2] = { pbuf + (jg * 2 + 0) * 2048, pbuf + (jg * 2 + 1) * 2048 };

  short8 bfr[2][2][4];   // [slot][ks][ni] register double-buffer of WhT frags

#define LOADB(CH, SL)                                                        \
  {                                                                          \
    _Pragma("unroll")                                                        \
    for (int ks = 0; ks < 2; ++ks)                                           \
      _Pragma("unroll")                                                      \
      for (int ni = 0; ni < 4; ++ni)                                         \
        bfr[SL][ks][ni] = *(const short8*)(wb + (size_t)(ni * 16 + l15) * NN + \
                                           jgbase + (CH) * JC + ks * 32 + c * 8); \
  }

#define BUILDC(CH, BB)                                                       \
  {                                                                          \
    const unsigned int mwv = (unsigned int)qw[(CH) >> 2];                    \
    const float* s2p = s2s + jgbase + (CH) * JC + jseg * 8;                  \
    f32x4 sa = *(const f32x4*)s2p;                                           \
    f32x4 sb = *(const f32x4*)(s2p + 4);                                     \
    float pv[8];                                                             \
    _Pragma("unroll")                                                        \
    for (int e = 0; e < 4; ++e) {                                            \
      float ev = s1r + sa[e];                                                \
      ev = fmaxf(ev, ALPHA_F * ev);                                          \
      pv[e] = ((mwv >> (((CH) & 3) * 8 + e)) & 1u) ? __expf(ev) : 0.f;       \
    }                                                                        \
    _Pragma("unroll")                                                        \
    for (int e = 0; e < 4; ++e) {                                            \
      float ev = s1r + sb[e];                                                \
      ev = fmaxf(ev, ALPHA_F * ev);                                          \
      pv[4 + e] = ((mwv >> (((CH) & 3) * 8 + 4 + e)) & 1u) ? __expf(ev) : 0.f; \
    }                                                                        \
    lacc += ((pv[0] + pv[1]) + (pv[2] + pv[3])) +                            \
            ((pv[4] + pv[5]) + (pv[6] + pv[7]));                             \
    i32x4 pk;                                                                \
    pk[0] = (int)cvtpk(pv[0], pv[1]);                                        \
    pk[1] = (int)cvtpk(pv[2], pv[3]);                                        \
    pk[2] = (int)cvtpk(pv[4], pv[5]);                                        \
    pk[3] = (int)cvtpk(pv[6], pv[7]);                                        \
    *(i32x4*)(pbW[BB] + row * 64 + gsw * 8) = pk;                            \
  }

  // raw barrier: drain LDS ops only; global loads stay counted (T4)
#define CHUNK_BARRIER()                                                      \
  { asm volatile("s_waitcnt lgkmcnt(0)" ::: "memory");                       \
    __builtin_amdgcn_s_barrier(); }

  __syncthreads();   // s2s + lsml ready

  BUILDC(0, 0)
  LOADB(0, 0)        // chunk 0's bfr: issued before barrier, used after
  CHUNK_BARRIER()

#pragma unroll
  for (int ch = 0; ch < NCH; ++ch) {
    const int bb = ch & 1;
    const unsigned short* pbR = pbW[bb];
    // issue next chunk's bfr first (longest latency, hidden by BUILD+MFMA)
    if (ch + 1 < NCH) LOADB(ch + 1, (ch + 1) & 1)
    if (ch + 1 < NCH) BUILDC(ch + 1, (ch + 1) & 1)
    // consume current bfr (in flight since previous iteration)
#pragma unroll
    for (int ks = 0; ks < 2; ++ks) {
      short8 a0 = *(const short8*)(pbR + (0 * 16 + l15) * 64 +
                                   (((ks * 4 + c) ^ (l15 & 7)) * 8));
      short8 a1 = *(const short8*)(pbR + (1 * 16 + l15) * 64 +
                                   (((ks * 4 + c) ^ (l15 & 7)) * 8));
#pragma unroll
      for (int ni = 0; ni < 4; ++ni) {
        acc[0][ni] = __builtin_amdgcn_mfma_f32_16x16x32_bf16(
            a0, bfr[bb][ks][ni], acc[0][ni], 0, 0, 0);
        acc[1][ni] = __builtin_amdgcn_mfma_f32_16x16x32_bf16(
            a1, bfr[bb][ks][ni], acc[1][ni], 0, 0, 0);
      }
    }
    CHUNK_BARRIER()
  }

  // lsum: pre-reduce the duplicate row within the wave, then one atomic
  lacc += __shfl_xor(lacc, 32, 64);
  if (lane < 32) atomicAdd(&lsml[row], lacc);
  __syncthreads();

  // combine j-group partial accumulators via LDS
  if (jg == 1) {
#pragma unroll
    for (int mi = 0; mi < 2; ++mi)
#pragma unroll
      for (int r = 0; r < 4; ++r) {
        const int rr = mi * 16 + c * 4 + r;
#pragma unroll
        for (int ni = 0; ni < 4; ++ni)
          comb[rr * ND + wcol * 64 + ni * 16 + l15] = acc[mi][ni][r];
      }
  }
  __syncthreads();
  if (jg == 0) {
    float* ob = out + ((size_t)b * NN + i0) * ND + wcol * 64;
#pragma unroll
    for (int mi = 0; mi < 2; ++mi)
#pragma unroll
      for (int r = 0; r < 4; ++r) {
        const int rr = mi * 16 + c * 4 + r;
        const float linv = 1.0f / lsml[rr];
#pragma unroll
        for (int ni = 0; ni < 4; ++ni) {
          const float v = acc[mi][ni][r] + comb[rr * ND + wcol * 64 + ni * 16 + l15];
          ob[(size_t)rr * ND + ni * 16 + l15] = v * linv;
        }
      }
  }
#undef BUILDC
#undef LOADB
#undef CHUNK_BARRIER
}

extern "C" void kernel_launch(void* const* d_in, const int* in_sizes, int n_in,
                              void* d_out, int out_size, void* d_ws, size_t ws_size,
                              hipStream_t stream) {
  const float* h   = (const float*)d_in[0];
  const int*   adj = (const int*)d_in[1];
  const float* W   = (const float*)d_in[2];
  const float* a   = (const float*)d_in[3];
  float* out = (float*)d_out;

  unsigned short* WhT = (unsigned short*)d_ws;                       // 8 MB bf16
  float* s1g = (float*)((char*)d_ws + (size_t)NB * ND * NN * 2);     // 64 KB
  float* s2g = s1g + (size_t)NB * NN;                                // 64 KB
  i32x4* adjbits = (i32x4*)(s2g + (size_t)NB * NN);                  // 4 MB

  k_pre<<<dim3(WHB + NB * 2 * 2 * 64), dim3(256), 0, stream>>>(
      adj, (uint2*)adjbits, h, W, a, WhT, s1g, s2g);
  k_attn<<<dim3(NB * NN / 32), dim3(512), 0, stream>>>(adjbits, WhT, s1g, s2g, out);
}

// Round 10
// 98.591 us; speedup vs baseline: 1.2470x; 1.0028x over previous
//
#include <hip/hip_runtime.h>
#include <cstdint>
#include <cstddef>

// GraphAttentionLayer fused: B=8, N=2048, D=256
//  k_pre:  heterogeneous pre-pass. Blocks 0..255: Wh = h @ W^T (bf16 MFMA) ->
//          WhT[b][d][n] bf16 + s1,s2 f32. Blocks 256..767: adj -> bitmap as a
//          LOOPED streaming pack (8 units/thread, unroll 2): continuous load
//          issue like m13/m146 streams, replacing R9's one-shot burst that
//          capped at ~2.6 TB/s (no software pipelining in straight-line code).
//  k_attn: out[i,:] = (sum_j exp(lrelu(s1_i+s2_j))*mask_ij * Wh[j,:]) / l_i
//          (v8 structure, unchanged: P built once in LDS, bitmap masks from
//          registers, bfr register double-buffer across raw counted barriers.)

#define NB 8
#define NN 2048
#define ND 256
#define ALPHA_F 0.2f
#define JC 64          // j per chunk
#define NCH 16         // chunks per j-group (1024/64)
#define WHB 256        // wh blocks (NB*NN/64)
#define PKB 512        // pack blocks (looped)

typedef __attribute__((ext_vector_type(8))) short short8;   // bf16x8 MFMA frag
typedef __attribute__((ext_vector_type(4))) float f32x4;    // MFMA acc frag
typedef __attribute__((ext_vector_type(4))) int   i32x4;

__device__ __forceinline__ unsigned short f2bf(float f) {
  union { float f; unsigned int u; } v; v.f = f;
  unsigned int r = v.u + 0x7FFFu + ((v.u >> 16) & 1u);   // RNE
  return (unsigned short)(r >> 16);
}

__device__ __forceinline__ short8 pack8(const float* v) {
  short8 r;
#pragma unroll
  for (int e = 0; e < 8; ++e) r[e] = (short)f2bf(v[e]);
  return r;
}

__device__ __forceinline__ unsigned int cvtpk(float lo, float hi) {
  unsigned int r;
  asm("v_cvt_pk_bf16_f32 %0, %1, %2" : "=v"(r) : "v"(lo), "v"(hi));
  return r;
}

// ---------------- kernel 0+1 fused: wh (0..255) | pack (256..767) ----------
__global__ __launch_bounds__(256) void k_pre(
    const int* __restrict__ adj, unsigned int* __restrict__ adjbitsw,
    const float* __restrict__ h, const float* __restrict__ W,
    const float* __restrict__ a,
    unsigned short* __restrict__ WhT, float* __restrict__ s1g,
    float* __restrict__ s2g)
{
  __shared__ float sl1[64], sl2[64];
  const int tid = threadIdx.x;

  if (blockIdx.x >= WHB) {
    // ---- pack: adj -> bitmap, LOOPED stream. Unit = (b,jg,r,ib): thread
    // (row,jseg) loads 4 chunks x 8 ints (8 x 16-B, line-contiguous per wave)
    // and packs one 32-bit word (word r of k_attn's per-thread i32x4). ----
    const int pblk = blockIdx.x - WHB;   // 0..511
    const int row  = tid >> 3;           // 0..31
    const int jseg = tid & 7;            // 0..7
#pragma unroll 2
    for (int k = 0; k < 8; ++k) {
      const int ublk = pblk * 8 + k;     // (((b*2+jg)*4 + r)*64 + ib)
      const int ib   = ublk & 63;
      const int r    = (ublk >> 6) & 3;
      const int jg   = (ublk >> 8) & 1;
      const int b    = ublk >> 9;
      const int i    = ib * 32 + row;
      const int* ap0 = adj + ((size_t)b * NN + i) * NN + jg * (NN / 2) +
                       r * 4 * JC + jseg * 8;
      i32x4 t0[4], t1[4];
#pragma unroll
      for (int cc = 0; cc < 4; ++cc) {
        const int* ap = ap0 + cc * JC;
        t0[cc] = *(const i32x4*)ap;
        t1[cc] = *(const i32x4*)(ap + 4);
      }
      unsigned int w = 0;
#pragma unroll
      for (int cc = 0; cc < 4; ++cc)
#pragma unroll
        for (int e = 0; e < 4; ++e) {
          w |= ((unsigned int)t0[cc][e]) << (cc * 8 + e);
          w |= ((unsigned int)t1[cc][e]) << (cc * 8 + 4 + e);
        }
      adjbitsw[((((size_t)b * 2 + jg) * NN + i) * 8 + jseg) * 4 + r] = w;
    }
    return;
  }

  // ---- wh: Wh = h @ W^T, s1/s2 from f32 acc, WhT store -------------------
  const int wid  = tid >> 6;
  const int lane = tid & 63;
  const int l15  = lane & 15;
  const int c    = lane >> 4;
  const int r0   = blockIdx.x * 64;   // flattened (b,n) row base
  const int b    = r0 >> 11;
  const int n0   = r0 & 2047;

  if (tid < 64) { sl1[tid] = 0.f; sl2[tid] = 0.f; }

  f32x4 acc[4][4] = {};

  const float* hb = h + (size_t)r0 * ND;
  const int ocol0 = wid * 64;

  for (int k0 = 0; k0 < ND; k0 += 32) {
    short8 afr[4], bfr[4];
#pragma unroll
    for (int mi = 0; mi < 4; ++mi) {
      const float* p = hb + (size_t)(mi * 16 + l15) * ND + k0 + c * 8;
      float t[8];
      *(f32x4*)t       = *(const f32x4*)p;
      *(f32x4*)(t + 4) = *(const f32x4*)(p + 4);
      afr[mi] = pack8(t);
    }
#pragma unroll
    for (int ni = 0; ni < 4; ++ni) {
      const int o = ocol0 + ni * 16 + l15;
      const float* p = W + (size_t)o * ND + k0 + c * 8;
      float t[8];
      *(f32x4*)t       = *(const f32x4*)p;
      *(f32x4*)(t + 4) = *(const f32x4*)(p + 4);
      bfr[ni] = pack8(t);
    }
#pragma unroll
    for (int mi = 0; mi < 4; ++mi)
#pragma unroll
      for (int ni = 0; ni < 4; ++ni)
        acc[mi][ni] = __builtin_amdgcn_mfma_f32_16x16x32_bf16(
            afr[mi], bfr[ni], acc[mi][ni], 0, 0, 0);
  }

  float a1v[4], a2v[4];
#pragma unroll
  for (int ni = 0; ni < 4; ++ni) {
    const int o = ocol0 + ni * 16 + l15;
    a1v[ni] = a[o];
    a2v[ni] = a[ND + o];
  }
  float p1[4][4] = {}, p2[4][4] = {};
#pragma unroll
  for (int mi = 0; mi < 4; ++mi)
#pragma unroll
    for (int ni = 0; ni < 4; ++ni)
#pragma unroll
      for (int r = 0; r < 4; ++r) {
        p1[mi][r] += acc[mi][ni][r] * a1v[ni];
        p2[mi][r] += acc[mi][ni][r] * a2v[ni];
      }
#pragma unroll
  for (int m = 1; m <= 8; m <<= 1) {
#pragma unroll
    for (int mi = 0; mi < 4; ++mi)
#pragma unroll
      for (int r = 0; r < 4; ++r) {
        p1[mi][r] += __shfl_xor(p1[mi][r], m, 64);
        p2[mi][r] += __shfl_xor(p2[mi][r], m, 64);
      }
  }
  __syncthreads();
  if (l15 == 0) {
#pragma unroll
    for (int mi = 0; mi < 4; ++mi)
#pragma unroll
      for (int r = 0; r < 4; ++r) {
        atomicAdd(&sl1[mi * 16 + c * 4 + r], p1[mi][r]);
        atomicAdd(&sl2[mi * 16 + c * 4 + r], p2[mi][r]);
      }
  }

#pragma unroll
  for (int mi = 0; mi < 4; ++mi)
#pragma unroll
    for (int ni = 0; ni < 4; ++ni) {
      const int o = ocol0 + ni * 16 + l15;
      const int n = n0 + mi * 16 + c * 4;
      unsigned short u4[4];
#pragma unroll
      for (int r = 0; r < 4; ++r) u4[r] = f2bf(acc[mi][ni][r]);
      *(uint2*)(WhT + ((size_t)b * ND + o) * NN + n) = *(uint2*)u4;
    }
  __syncthreads();
  if (tid < 64) { s1g[r0 + tid] = sl1[tid]; s2g[r0 + tid] = sl2[tid]; }
}

// ---------------- kernel 2: fused masked-exp attention GEMM (v8) -----------
// grid: 512 blocks 1D (b = bid&7 for XCD/L2 locality), 512 thr (8 waves).
// Wave wid: j-group = wid>>2 (half of j-range), col-group = wid&3 (64 cols).
// Per chunk of 64 j: 256 threads of a j-group build P[32][64] bf16 in LDS
// (swizzled) gated by prologue-loaded bitmap bits; the 4 waves consume P as
// MFMA A-frags. Double-buffered pbuf AND register-double-buffered bfr: next
// chunk's WhT frag loads issue one full chunk before use, staying in flight
// across the raw (lgkmcnt-only) barrier.
__global__ __launch_bounds__(512, 4) void k_attn(
    const i32x4* __restrict__ adjbits, const unsigned short* __restrict__ WhT,
    const float* __restrict__ s1g, const float* __restrict__ s2g,
    float* __restrict__ out)
{
  __shared__ __align__(16) char smem[32 * 1024 + 128];
  float*          s2s  = (float*)smem;                       // [0, 8K)
  unsigned short* pbuf = (unsigned short*)(smem + 8 * 1024); // [8K,24K): [jg][buf][32][64]
  float*          lsml = (float*)(smem + 32 * 1024);         // [32K, +128)
  float*          comb = (float*)smem;                       // [0,32K) alias after loop

  const int tid  = threadIdx.x;
  const int wid  = tid >> 6;
  const int lane = tid & 63;
  const int l15  = lane & 15;
  const int c    = lane >> 4;
  const int bid  = blockIdx.x;
  const int b    = bid & 7;           // batch -> XCD residue (L2 locality)
  const int i0   = (bid >> 3) * 32;

  // build-phase thread mapping
  const int lt     = tid & 255;
  const int jg     = tid >> 8;        // j-group 0/1 (== wid>>2)
  const int row    = lt & 31;
  const int jseg   = lt >> 5;         // 0..7, 8 j's each
  const int jgbase = jg * (NN / 2);
  const int gsw    = jseg ^ (row & 7);          // swizzled 16B granule
  const int wcol   = wid & 3;

  if (tid < 32) lsml[tid] = 0.f;
  { // stage s2[b][:] into LDS
    const f32x4* src = (const f32x4*)(s2g + (size_t)b * NN);
    f32x4* dst = (f32x4*)s2s;
    for (int t = tid; t < NN / 4; t += 512) dst[t] = src[t];
  }
  const float s1r = s1g[(size_t)b * NN + i0 + row];

  // masks for all 16 chunks: one 16-B load (byte ch of qw[ch>>2])
  const i32x4 qw = adjbits[(((size_t)b * 2 + jg) * NN + (i0 + row)) * 8 + jseg];

  f32x4 acc[2][4] = {};
  float lacc = 0.f;

  const unsigned short* wb = WhT + ((size_t)b * ND + wcol * 64) * NN;
  unsigned short* pbW[2] = { pbuf + (jg * 2 + 0) * 2048, pbuf + (jg * 2 + 1) * 2048 };

  short8 bfr[2][2][4];   // [slot][ks][ni] register double-buffer of WhT frags

#define LOADB(CH, SL)                                                        \
  {                                                                          \
    _Pragma("unroll")                                                        \
    for (int ks = 0; ks < 2; ++ks)                                           \
      _Pragma("unroll")                                                      \
      for (int ni = 0; ni < 4; ++ni)                                         \
        bfr[SL][ks][ni] = *(const short8*)(wb + (size_t)(ni * 16 + l15) * NN + \
                                           jgbase + (CH) * JC + ks * 32 + c * 8); \
  }

#define BUILDC(CH, BB)                                                       \
  {                                                                          \
    const unsigned int mwv = (unsigned int)qw[(CH) >> 2];                    \
    const float* s2p = s2s + jgbase + (CH) * JC + jseg * 8;                  \
    f32x4 sa = *(const f32x4*)s2p;                                           \
    f32x4 sb = *(const f32x4*)(s2p + 4);                                     \
    float pv[8];                                                             \
    _Pragma("unroll")                                                        \
    for (int e = 0; e < 4; ++e) {                                            \
      float ev = s1r + sa[e];                                                \
      ev = fmaxf(ev, ALPHA_F * ev);                                          \
      pv[e] = ((mwv >> (((CH) & 3) * 8 + e)) & 1u) ? __expf(ev) : 0.f;       \
    }                                                                        \
    _Pragma("unroll")                                                        \
    for (int e = 0; e < 4; ++e) {                                            \
      float ev = s1r + sb[e];                                                \
      ev = fmaxf(ev, ALPHA_F * ev);                                          \
      pv[4 + e] = ((mwv >> (((CH) & 3) * 8 + 4 + e)) & 1u) ? __expf(ev) : 0.f; \
    }                                                                        \
    lacc += ((pv[0] + pv[1]) + (pv[2] + pv[3])) +                            \
            ((pv[4] + pv[5]) + (pv[6] + pv[7]));                             \
    i32x4 pk;                                                                \
    pk[0] = (int)cvtpk(pv[0], pv[1]);                                        \
    pk[1] = (int)cvtpk(pv[2], pv[3]);                                        \
    pk[2] = (int)cvtpk(pv[4], pv[5]);                                        \
    pk[3] = (int)cvtpk(pv[6], pv[7]);                                        \
    *(i32x4*)(pbW[BB] + row * 64 + gsw * 8) = pk;                            \
  }

  // raw barrier: drain LDS ops only; global loads stay counted (T4)
#define CHUNK_BARRIER()                                                      \
  { asm volatile("s_waitcnt lgkmcnt(0)" ::: "memory");                       \
    __builtin_amdgcn_s_barrier(); }

  __syncthreads();   // s2s + lsml ready

  BUILDC(0, 0)
  LOADB(0, 0)        // chunk 0's bfr: issued before barrier, used after
  CHUNK_BARRIER()

#pragma unroll
  for (int ch = 0; ch < NCH; ++ch) {
    const int bb = ch & 1;
    const unsigned short* pbR = pbW[bb];
    // issue next chunk's bfr first (longest latency, hidden by BUILD+MFMA)
    if (ch + 1 < NCH) LOADB(ch + 1, (ch + 1) & 1)
    if (ch + 1 < NCH) BUILDC(ch + 1, (ch + 1) & 1)
    // consume current bfr (in flight since previous iteration)
#pragma unroll
    for (int ks = 0; ks < 2; ++ks) {
      short8 a0 = *(const short8*)(pbR + (0 * 16 + l15) * 64 +
                                   (((ks * 4 + c) ^ (l15 & 7)) * 8));
      short8 a1 = *(const short8*)(pbR + (1 * 16 + l15) * 64 +
                                   (((ks * 4 + c) ^ (l15 & 7)) * 8));
#pragma unroll
      for (int ni = 0; ni < 4; ++ni) {
        acc[0][ni] = __builtin_amdgcn_mfma_f32_16x16x32_bf16(
            a0, bfr[bb][ks][ni], acc[0][ni], 0, 0, 0);
        acc[1][ni] = __builtin_amdgcn_mfma_f32_16x16x32_bf16(
            a1, bfr[bb][ks][ni], acc[1][ni], 0, 0, 0);
      }
    }
    CHUNK_BARRIER()
  }

  // lsum: pre-reduce the duplicate row within the wave, then one atomic
  lacc += __shfl_xor(lacc, 32, 64);
  if (lane < 32) atomicAdd(&lsml[row], lacc);
  __syncthreads();

  // combine j-group partial accumulators via LDS
  if (jg == 1) {
#pragma unroll
    for (int mi = 0; mi < 2; ++mi)
#pragma unroll
      for (int r = 0; r < 4; ++r) {
        const int rr = mi * 16 + c * 4 + r;
#pragma unroll
        for (int ni = 0; ni < 4; ++ni)
          comb[rr * ND + wcol * 64 + ni * 16 + l15] = acc[mi][ni][r];
      }
  }
  __syncthreads();
  if (jg == 0) {
    float* ob = out + ((size_t)b * NN + i0) * ND + wcol * 64;
#pragma unroll
    for (int mi = 0; mi < 2; ++mi)
#pragma unroll
      for (int r = 0; r < 4; ++r) {
        const int rr = mi * 16 + c * 4 + r;
        const float linv = 1.0f / lsml[rr];
#pragma unroll
        for (int ni = 0; ni < 4; ++ni) {
          const float v = acc[mi][ni][r] + comb[rr * ND + wcol * 64 + ni * 16 + l15];
          ob[(size_t)rr * ND + ni * 16 + l15] = v * linv;
        }
      }
  }
#undef BUILDC
#undef LOADB
#undef CHUNK_BARRIER
}

extern "C" void kernel_launch(void* const* d_in, const int* in_sizes, int n_in,
                              void* d_out, int out_size, void* d_ws, size_t ws_size,
                              hipStream_t stream) {
  const float* h   = (const float*)d_in[0];
  const int*   adj = (const int*)d_in[1];
  const float* W   = (const float*)d_in[2];
  const float* a   = (const float*)d_in[3];
  float* out = (float*)d_out;

  unsigned short* WhT = (unsigned short*)d_ws;                       // 8 MB bf16
  float* s1g = (float*)((char*)d_ws + (size_t)NB * ND * NN * 2);     // 64 KB
  float* s2g = s1g + (size_t)NB * NN;                                // 64 KB
  i32x4* adjbits = (i32x4*)(s2g + (size_t)NB * NN);                  // 4 MB

  k_pre<<<dim3(WHB + PKB), dim3(256), 0, stream>>>(
      adj, (unsigned int*)adjbits, h, W, a, WhT, s1g, s2g);
  k_attn<<<dim3(NB * NN / 32), dim3(512), 0, stream>>>(adjbits, WhT, s1g, s2g, out);
}

// Round 11
// 98.047 us; speedup vs baseline: 1.2539x; 1.0055x over previous
//
#include <hip/hip_runtime.h>
#include <cstdint>
#include <cstddef>

// GraphAttentionLayer fused: B=8, N=2048, D=256
//  k_pre:  heterogeneous pre-pass. Blocks 0..255: Wh = h @ W^T (bf16 MFMA) ->
//          WhT[b][d][n] bf16 + s1,s2 f32. Blocks 256..1279: adj -> bitmap with
//          FULLY DENSE wave loads (lane*16B contiguous, 1KB/instr — the m13
//          pattern) + LDS nibble redistribution to the bitmap word layout.
//          All previous pack variants used 16B@32B-stride lane mappings and
//          capped at ~2.4 TB/s (half-used lines, MSHR-fragmented).
//  k_attn: out[i,:] = (sum_j exp(lrelu(s1_i+s2_j))*mask_ij * Wh[j,:]) / l_i
//          (v8 structure, unchanged.)

#define NB 8
#define NN 2048
#define ND 256
#define ALPHA_F 0.2f
#define JC 64          // j per chunk
#define NCH 16         // chunks per j-group (1024/64)
#define WHB 256        // wh blocks (NB*NN/64)
#define PKB 1024       // pack blocks (16 rows each)

typedef __attribute__((ext_vector_type(8))) short short8;   // bf16x8 MFMA frag
typedef __attribute__((ext_vector_type(4))) float f32x4;    // MFMA acc frag
typedef __attribute__((ext_vector_type(4))) int   i32x4;

__device__ __forceinline__ unsigned short f2bf(float f) {
  union { float f; unsigned int u; } v; v.f = f;
  unsigned int r = v.u + 0x7FFFu + ((v.u >> 16) & 1u);   // RNE
  return (unsigned short)(r >> 16);
}

__device__ __forceinline__ short8 pack8(const float* v) {
  short8 r;
#pragma unroll
  for (int e = 0; e < 8; ++e) r[e] = (short)f2bf(v[e]);
  return r;
}

__device__ __forceinline__ unsigned int cvtpk(float lo, float hi) {
  unsigned int r;
  asm("v_cvt_pk_bf16_f32 %0, %1, %2" : "=v"(r) : "v"(lo), "v"(hi));
  return r;
}

// ---------------- kernel 0+1 fused: wh (0..255) | pack (256..1279) ---------
__global__ __launch_bounds__(256) void k_pre(
    const int* __restrict__ adj, unsigned int* __restrict__ adjbitsw,
    const float* __restrict__ h, const float* __restrict__ W,
    const float* __restrict__ a,
    unsigned short* __restrict__ WhT, float* __restrict__ s1g,
    float* __restrict__ s2g)
{
  __shared__ float sl1[64], sl2[64];
  __shared__ unsigned int nibs[16][64];   // [row][lane]: nibble sg*64+lane @ bits sg*4
  const int tid = threadIdx.x;

  if (blockIdx.x >= WHB) {
    // ---- pack: DENSE loads. Block = (b, 16-row group). Wave w reads rows
    // w*4..w*4+3; per row 8 instructions of lane-contiguous 1KB. Lane packs
    // 4 ints -> 1 nibble per load; 8 nibbles -> u32 in LDS. Phase 2 builds
    // bitmap words (byte cc of word (i,jg,jseg,r) = row-byte
    // jg*128+r*32+cc*8+jseg = nibbles 2K,2K+1) and stores 16B per thread.
    const int pb = blockIdx.x - WHB;   // 0..1023
    const int b  = pb >> 7;            // 0..7
    const int ib = pb & 127;           // rows ib*16 .. +16
    const int w  = tid >> 6;
    const int l  = tid & 63;

    const int* rowbase = adj + (size_t)(b * NN + ib * 16 + w * 4) * NN;
#pragma unroll 2
    for (int rr = 0; rr < 4; ++rr) {
      const int* rp = rowbase + (size_t)rr * NN;
      i32x4 t[8];
#pragma unroll
      for (int sg = 0; sg < 8; ++sg)
        t[sg] = *(const i32x4*)(rp + sg * 256 + l * 4);   // lane-dense 1KB
      unsigned int nw = 0;
#pragma unroll
      for (int sg = 0; sg < 8; ++sg) {
        const unsigned int nib =
            ((unsigned int)t[sg][0] & 1u)        | (((unsigned int)t[sg][1] & 1u) << 1) |
            (((unsigned int)t[sg][2] & 1u) << 2) | (((unsigned int)t[sg][3] & 1u) << 3);
        nw |= nib << (sg * 4);
      }
      nibs[w * 4 + rr][l] = nw;
    }
    __syncthreads();

    const int i_row = tid >> 4;        // 0..15
    const int jg    = (tid >> 3) & 1;  // 0..1
    const int jseg  = tid & 7;         // 0..7
    unsigned int wout[4];
#pragma unroll
    for (int r = 0; r < 4; ++r) {
      unsigned int word = 0;
#pragma unroll
      for (int cc = 0; cc < 4; ++cc) {
        const int K  = jg * 128 + r * 32 + cc * 8 + jseg;  // byte index in row
        const int n0 = 2 * K;                              // even -> same sg as n0+1
        const int sh = (n0 >> 6) * 4;
        const unsigned int lo = (nibs[i_row][n0 & 63]       >> sh) & 0xFu;
        const unsigned int hi = (nibs[i_row][(n0 + 1) & 63] >> sh) & 0xFu;
        word |= (lo | (hi << 4)) << (cc * 8);
      }
      wout[r] = word;
    }
    i32x4 wv; wv[0] = (int)wout[0]; wv[1] = (int)wout[1];
    wv[2] = (int)wout[2]; wv[3] = (int)wout[3];
    *(i32x4*)(adjbitsw +
              ((((size_t)b * 2 + jg) * NN + (ib * 16 + i_row)) * 8 + jseg) * 4) = wv;
    return;
  }

  // ---- wh: Wh = h @ W^T, s1/s2 from f32 acc, WhT store -------------------
  const int wid  = tid >> 6;
  const int lane = tid & 63;
  const int l15  = lane & 15;
  const int c    = lane >> 4;
  const int r0   = blockIdx.x * 64;   // flattened (b,n) row base
  const int b    = r0 >> 11;
  const int n0   = r0 & 2047;

  if (tid < 64) { sl1[tid] = 0.f; sl2[tid] = 0.f; }

  f32x4 acc[4][4] = {};

  const float* hb = h + (size_t)r0 * ND;
  const int ocol0 = wid * 64;

  for (int k0 = 0; k0 < ND; k0 += 32) {
    short8 afr[4], bfr[4];
#pragma unroll
    for (int mi = 0; mi < 4; ++mi) {
      const float* p = hb + (size_t)(mi * 16 + l15) * ND + k0 + c * 8;
      float t[8];
      *(f32x4*)t       = *(const f32x4*)p;
      *(f32x4*)(t + 4) = *(const f32x4*)(p + 4);
      afr[mi] = pack8(t);
    }
#pragma unroll
    for (int ni = 0; ni < 4; ++ni) {
      const int o = ocol0 + ni * 16 + l15;
      const float* p = W + (size_t)o * ND + k0 + c * 8;
      float t[8];
      *(f32x4*)t       = *(const f32x4*)p;
      *(f32x4*)(t + 4) = *(const f32x4*)(p + 4);
      bfr[ni] = pack8(t);
    }
#pragma unroll
    for (int mi = 0; mi < 4; ++mi)
#pragma unroll
      for (int ni = 0; ni < 4; ++ni)
        acc[mi][ni] = __builtin_amdgcn_mfma_f32_16x16x32_bf16(
            afr[mi], bfr[ni], acc[mi][ni], 0, 0, 0);
  }

  float a1v[4], a2v[4];
#pragma unroll
  for (int ni = 0; ni < 4; ++ni) {
    const int o = ocol0 + ni * 16 + l15;
    a1v[ni] = a[o];
    a2v[ni] = a[ND + o];
  }
  float p1[4][4] = {}, p2[4][4] = {};
#pragma unroll
  for (int mi = 0; mi < 4; ++mi)
#pragma unroll
    for (int ni = 0; ni < 4; ++ni)
#pragma unroll
      for (int r = 0; r < 4; ++r) {
        p1[mi][r] += acc[mi][ni][r] * a1v[ni];
        p2[mi][r] += acc[mi][ni][r] * a2v[ni];
      }
#pragma unroll
  for (int m = 1; m <= 8; m <<= 1) {
#pragma unroll
    for (int mi = 0; mi < 4; ++mi)
#pragma unroll
      for (int r = 0; r < 4; ++r) {
        p1[mi][r] += __shfl_xor(p1[mi][r], m, 64);
        p2[mi][r] += __shfl_xor(p2[mi][r], m, 64);
      }
  }
  __syncthreads();
  if (l15 == 0) {
#pragma unroll
    for (int mi = 0; mi < 4; ++mi)
#pragma unroll
      for (int r = 0; r < 4; ++r) {
        atomicAdd(&sl1[mi * 16 + c * 4 + r], p1[mi][r]);
        atomicAdd(&sl2[mi * 16 + c * 4 + r], p2[mi][r]);
      }
  }

#pragma unroll
  for (int mi = 0; mi < 4; ++mi)
#pragma unroll
    for (int ni = 0; ni < 4; ++ni) {
      const int o = ocol0 + ni * 16 + l15;
      const int n = n0 + mi * 16 + c * 4;
      unsigned short u4[4];
#pragma unroll
      for (int r = 0; r < 4; ++r) u4[r] = f2bf(acc[mi][ni][r]);
      *(uint2*)(WhT + ((size_t)b * ND + o) * NN + n) = *(uint2*)u4;
    }
  __syncthreads();
  if (tid < 64) { s1g[r0 + tid] = sl1[tid]; s2g[r0 + tid] = sl2[tid]; }
}

// ---------------- kernel 2: fused masked-exp attention GEMM (v8) -----------
// grid: 512 blocks 1D (b = bid&7 for XCD/L2 locality), 512 thr (8 waves).
// Wave wid: j-group = wid>>2 (half of j-range), col-group = wid&3 (64 cols).
// Per chunk of 64 j: 256 threads of a j-group build P[32][64] bf16 in LDS
// (swizzled) gated by prologue-loaded bitmap bits; the 4 waves consume P as
// MFMA A-frags. Double-buffered pbuf AND register-double-buffered bfr.
__global__ __launch_bounds__(512, 4) void k_attn(
    const i32x4* __restrict__ adjbits, const unsigned short* __restrict__ WhT,
    const float* __restrict__ s1g, const float* __restrict__ s2g,
    float* __restrict__ out)
{
  __shared__ __align__(16) char smem[32 * 1024 + 128];
  float*          s2s  = (float*)smem;                       // [0, 8K)
  unsigned short* pbuf = (unsigned short*)(smem + 8 * 1024); // [8K,24K): [jg][buf][32][64]
  float*          lsml = (float*)(smem + 32 * 1024);         // [32K, +128)
  float*          comb = (float*)smem;                       // [0,32K) alias after loop

  const int tid  = threadIdx.x;
  const int wid  = tid >> 6;
  const int lane = tid & 63;
  const int l15  = lane & 15;
  const int c    = lane >> 4;
  const int bid  = blockIdx.x;
  const int b    = bid & 7;           // batch -> XCD residue (L2 locality)
  const int i0   = (bid >> 3) * 32;

  // build-phase thread mapping
  const int lt     = tid & 255;
  const int jg     = tid >> 8;        // j-group 0/1 (== wid>>2)
  const int row    = lt & 31;
  const int jseg   = lt >> 5;         // 0..7, 8 j's each
  const int jgbase = jg * (NN / 2);
  const int gsw    = jseg ^ (row & 7);          // swizzled 16B granule
  const int wcol   = wid & 3;

  if (tid < 32) lsml[tid] = 0.f;
  { // stage s2[b][:] into LDS
    const f32x4* src = (const f32x4*)(s2g + (size_t)b * NN);
    f32x4* dst = (f32x4*)s2s;
    for (int t = tid; t < NN / 4; t += 512) dst[t] = src[t];
  }
  const float s1r = s1g[(size_t)b * NN + i0 + row];

  // masks for all 16 chunks: one 16-B load (byte ch of qw[ch>>2])
  const i32x4 qw = adjbits[(((size_t)b * 2 + jg) * NN + (i0 + row)) * 8 + jseg];

  f32x4 acc[2][4] = {};
  float lacc = 0.f;

  const unsigned short* wb = WhT + ((size_t)b * ND + wcol * 64) * NN;
  unsigned short* pbW[2] = { pbuf + (jg * 2 + 0) * 2048, pbuf + (jg * 2 + 1) * 2048 };

  short8 bfr[2][2][4];   // [slot][ks][ni] register double-buffer of WhT frags

#define LOADB(CH, SL)                                                        \
  {                                                                          \
    _Pragma("unroll")                                                        \
    for (int ks = 0; ks < 2; ++ks)                                           \
      _Pragma("unroll")                                                      \
      for (int ni = 0; ni < 4; ++ni)                                         \
        bfr[SL][ks][ni] = *(const short8*)(wb + (size_t)(ni * 16 + l15) * NN + \
                                           jgbase + (CH) * JC + ks * 32 + c * 8); \
  }

#define BUILDC(CH, BB)                                                       \
  {                                                                          \
    const unsigned int mwv = (unsigned int)qw[(CH) >> 2];                    \
    const float* s2p = s2s + jgbase + (CH) * JC + jseg * 8;                  \
    f32x4 sa = *(const f32x4*)s2p;                                           \
    f32x4 sb = *(const f32x4*)(s2p + 4);                                     \
    float pv[8];                                                             \
    _Pragma("unroll")                                                        \
    for (int e = 0; e < 4; ++e) {                                            \
      float ev = s1r + sa[e];                                                \
      ev = fmaxf(ev, ALPHA_F * ev);                                          \
      pv[e] = ((mwv >> (((CH) & 3) * 8 + e)) & 1u) ? __expf(ev) : 0.f;       \
    }                                                                        \
    _Pragma("unroll")                                                        \
    for (int e = 0; e < 4; ++e) {                                            \
      float ev = s1r + sb[e];                                                \
      ev = fmaxf(ev, ALPHA_F * ev);                                          \
      pv[4 + e] = ((mwv >> (((CH) & 3) * 8 + 4 + e)) & 1u) ? __expf(ev) : 0.f; \
    }                                                                        \
    lacc += ((pv[0] + pv[1]) + (pv[2] + pv[3])) +                            \
            ((pv[4] + pv[5]) + (pv[6] + pv[7]));                             \
    i32x4 pk;                                                                \
    pk[0] = (int)cvtpk(pv[0], pv[1]);                                        \
    pk[1] = (int)cvtpk(pv[2], pv[3]);                                        \
    pk[2] = (int)cvtpk(pv[4], pv[5]);                                        \
    pk[3] = (int)cvtpk(pv[6], pv[7]);                                        \
    *(i32x4*)(pbW[BB] + row * 64 + gsw * 8) = pk;                            \
  }

  // raw barrier: drain LDS ops only; global loads stay counted (T4)
#define CHUNK_BARRIER()                                                      \
  { asm volatile("s_waitcnt lgkmcnt(0)" ::: "memory");                       \
    __builtin_amdgcn_s_barrier(); }

  __syncthreads();   // s2s + lsml ready

  BUILDC(0, 0)
  LOADB(0, 0)        // chunk 0's bfr: issued before barrier, used after
  CHUNK_BARRIER()

#pragma unroll
  for (int ch = 0; ch < NCH; ++ch) {
    const int bb = ch & 1;
    const unsigned short* pbR = pbW[bb];
    // issue next chunk's bfr first (longest latency, hidden by BUILD+MFMA)
    if (ch + 1 < NCH) LOADB(ch + 1, (ch + 1) & 1)
    if (ch + 1 < NCH) BUILDC(ch + 1, (ch + 1) & 1)
    // consume current bfr (in flight since previous iteration)
#pragma unroll
    for (int ks = 0; ks < 2; ++ks) {
      short8 a0 = *(const short8*)(pbR + (0 * 16 + l15) * 64 +
                                   (((ks * 4 + c) ^ (l15 & 7)) * 8));
      short8 a1 = *(const short8*)(pbR + (1 * 16 + l15) * 64 +
                                   (((ks * 4 + c) ^ (l15 & 7)) * 8));
#pragma unroll
      for (int ni = 0; ni < 4; ++ni) {
        acc[0][ni] = __builtin_amdgcn_mfma_f32_16x16x32_bf16(
            a0, bfr[bb][ks][ni], acc[0][ni], 0, 0, 0);
        acc[1][ni] = __builtin_amdgcn_mfma_f32_16x16x32_bf16(
            a1, bfr[bb][ks][ni], acc[1][ni], 0, 0, 0);
      }
    }
    CHUNK_BARRIER()
  }

  // lsum: pre-reduce the duplicate row within the wave, then one atomic
  lacc += __shfl_xor(lacc, 32, 64);
  if (lane < 32) atomicAdd(&lsml[row], lacc);
  __syncthreads();

  // combine j-group partial accumulators via LDS
  if (jg == 1) {
#pragma unroll
    for (int mi = 0; mi < 2; ++mi)
#pragma unroll
      for (int r = 0; r < 4; ++r) {
        const int rr = mi * 16 + c * 4 + r;
#pragma unroll
        for (int ni = 0; ni < 4; ++ni)
          comb[rr * ND + wcol * 64 + ni * 16 + l15] = acc[mi][ni][r];
      }
  }
  __syncthreads();
  if (jg == 0) {
    float* ob = out + ((size_t)b * NN + i0) * ND + wcol * 64;
#pragma unroll
    for (int mi = 0; mi < 2; ++mi)
#pragma unroll
      for (int r = 0; r < 4; ++r) {
        const int rr = mi * 16 + c * 4 + r;
        const float linv = 1.0f / lsml[rr];
#pragma unroll
        for (int ni = 0; ni < 4; ++ni) {
          const float v = acc[mi][ni][r] + comb[rr * ND + wcol * 64 + ni * 16 + l15];
          ob[(size_t)rr * ND + ni * 16 + l15] = v * linv;
        }
      }
  }
#undef BUILDC
#undef LOADB
#undef CHUNK_BARRIER
}

extern "C" void kernel_launch(void* const* d_in, const int* in_sizes, int n_in,
                              void* d_out, int out_size, void* d_ws, size_t ws_size,
                              hipStream_t stream) {
  const float* h   = (const float*)d_in[0];
  const int*   adj = (const int*)d_in[1];
  const float* W   = (const float*)d_in[2];
  const float* a   = (const float*)d_in[3];
  float* out = (float*)d_out;

  unsigned short* WhT = (unsigned short*)d_ws;                       // 8 MB bf16
  float* s1g = (float*)((char*)d_ws + (size_t)NB * ND * NN * 2);     // 64 KB
  float* s2g = s1g + (size_t)NB * NN;                                // 64 KB
  i32x4* adjbits = (i32x4*)(s2g + (size_t)NB * NN);                  // 4 MB

  k_pre<<<dim3(WHB + PKB), dim3(256), 0, stream>>>(
      adj, (unsigned int*)adjbits, h, W, a, WhT, s1g, s2g);
  k_attn<<<dim3(NB * NN / 32), dim3(512), 0, stream>>>(adjbits, WhT, s1g, s2g, out);
}